// Round 1
// baseline (3184.248 us; speedup 1.0000x reference)
//
#include <hip/hip_runtime.h>

#define CH 128
constexpr int cN2 = 25000, cN1 = 50000, cN0 = 100000;
constexpr int cE1 = 500000, cE2 = 1000000;
constexpr float cEPS = 1e-5f;

static inline int cdiv(int a, int b) { return (a + b - 1) / b; }

// per-channel sum and sum-of-squares over rows
__global__ __launch_bounds__(256) void colstats_kernel(const float* __restrict__ in, int n,
                                                       float* __restrict__ s1, float* __restrict__ s2) {
    int tid = threadIdx.x;
    int c = tid & 127;
    int h = tid >> 7;  // 0/1
    float a1 = 0.f, a2 = 0.f;
    for (int r = blockIdx.x * 2 + h; r < n; r += gridDim.x * 2) {
        float v = in[(size_t)r * CH + c];
        a1 += v;
        a2 += v * v;
    }
    __shared__ float l1[256], l2[256];
    l1[tid] = a1;
    l2[tid] = a2;
    __syncthreads();
    if (h == 0) {
        a1 += l1[tid + 128];
        a2 += l2[tid + 128];
        unsafeAtomicAdd(&s1[c], a1);
        unsafeAtomicAdd(&s2[c], a2);
    }
}

__global__ __launch_bounds__(256) void fill_inv_kernel(int* __restrict__ inv, int n) {
    int i = blockIdx.x * 256 + threadIdx.x;
    if (i < n) inv[i] = -1;
}

__global__ __launch_bounds__(256) void scatter_inv_kernel(const int* __restrict__ perm, int* __restrict__ inv, int m) {
    int i = blockIdx.x * 256 + threadIdx.x;
    if (i < m) inv[perm[i]] = i;
}

// out[j] = (inv[j]>=0 ? src[inv[j]] : colsum*inv_cnt) + res[j]
__global__ __launch_bounds__(256) void unpool_kernel(const float* __restrict__ src, const int* __restrict__ inv,
                                                     const float* __restrict__ colsum, float inv_cnt,
                                                     const float* __restrict__ res, float* __restrict__ out, int n) {
    int idx = blockIdx.x * 256 + threadIdx.x;
    if (idx >= n * 32) return;
    int j = idx >> 5;
    int c4 = (idx & 31) * 4;
    int iv = inv[j];
    float4 v;
    if (iv >= 0) {
        v = *(const float4*)&src[(size_t)iv * CH + c4];
    } else {
        v.x = colsum[c4 + 0] * inv_cnt;
        v.y = colsum[c4 + 1] * inv_cnt;
        v.z = colsum[c4 + 2] * inv_cnt;
        v.w = colsum[c4 + 3] * inv_cnt;
    }
    float rv = res[j];
    v.x += rv; v.y += rv; v.z += rv; v.w += rv;
    *(float4*)&out[(size_t)j * CH + c4] = v;
}

__global__ __launch_bounds__(256) void edge_deg_kernel(const int* __restrict__ col, const float* __restrict__ ew,
                                                       float* __restrict__ deg, int E) {
    int e = blockIdx.x * 256 + threadIdx.x;
    if (e < E) unsafeAtomicAdd(&deg[col[e]], ew[e]);
}

__global__ __launch_bounds__(256) void dinv_kernel(float* __restrict__ deg, int n) {
    int i = blockIdx.x * 256 + threadIdx.x;
    if (i < n) deg[i] = rsqrtf(deg[i] + 1.0f);  // self-loop weight 1 added analytically
}

// Out[n x 128] = A[n x 128] @ W[128 x 128], fp32. W in LDS; 4 rows x 4 cols per thread.
__global__ __launch_bounds__(256) void gemm128_kernel(const float* __restrict__ A, const float* __restrict__ W,
                                                      float* __restrict__ Out, int n) {
    __shared__ float Ws[CH * CH];
    int tid = threadIdx.x;
    for (int i = tid * 4; i < CH * CH; i += 256 * 4)
        *(float4*)&Ws[i] = *(const float4*)&W[i];
    __syncthreads();

    int rbase = blockIdx.x * 32 + (tid >> 5) * 4;
    int cc = (tid & 31) * 4;
    int r0 = min(rbase + 0, n - 1);
    int r1 = min(rbase + 1, n - 1);
    int r2 = min(rbase + 2, n - 1);
    int r3 = min(rbase + 3, n - 1);
    const float* p0 = A + (size_t)r0 * CH;
    const float* p1 = A + (size_t)r1 * CH;
    const float* p2 = A + (size_t)r2 * CH;
    const float* p3 = A + (size_t)r3 * CH;

    float acc0[4] = {0, 0, 0, 0}, acc1[4] = {0, 0, 0, 0}, acc2[4] = {0, 0, 0, 0}, acc3[4] = {0, 0, 0, 0};
#pragma unroll
    for (int k4 = 0; k4 < CH; k4 += 4) {
        float4 a0 = *(const float4*)(p0 + k4);
        float4 a1 = *(const float4*)(p1 + k4);
        float4 a2 = *(const float4*)(p2 + k4);
        float4 a3 = *(const float4*)(p3 + k4);
        float av0[4] = {a0.x, a0.y, a0.z, a0.w};
        float av1[4] = {a1.x, a1.y, a1.z, a1.w};
        float av2[4] = {a2.x, a2.y, a2.z, a2.w};
        float av3[4] = {a3.x, a3.y, a3.z, a3.w};
#pragma unroll
        for (int s = 0; s < 4; ++s) {
            float4 w = *(const float4*)&Ws[(k4 + s) * CH + cc];
            acc0[0] += av0[s] * w.x; acc0[1] += av0[s] * w.y; acc0[2] += av0[s] * w.z; acc0[3] += av0[s] * w.w;
            acc1[0] += av1[s] * w.x; acc1[1] += av1[s] * w.y; acc1[2] += av1[s] * w.z; acc1[3] += av1[s] * w.w;
            acc2[0] += av2[s] * w.x; acc2[1] += av2[s] * w.y; acc2[2] += av2[s] * w.z; acc2[3] += av2[s] * w.w;
            acc3[0] += av3[s] * w.x; acc3[1] += av3[s] * w.y; acc3[2] += av3[s] * w.z; acc3[3] += av3[s] * w.w;
        }
    }
    if (rbase + 0 < n) *(float4*)&Out[(size_t)(rbase + 0) * CH + cc] = make_float4(acc0[0], acc0[1], acc0[2], acc0[3]);
    if (rbase + 1 < n) *(float4*)&Out[(size_t)(rbase + 1) * CH + cc] = make_float4(acc1[0], acc1[1], acc1[2], acc1[3]);
    if (rbase + 2 < n) *(float4*)&Out[(size_t)(rbase + 2) * CH + cc] = make_float4(acc2[0], acc2[1], acc2[2], acc2[3]);
    if (rbase + 3 < n) *(float4*)&Out[(size_t)(rbase + 3) * CH + cc] = make_float4(acc3[0], acc3[1], acc3[2], acc3[3]);
}

// out[j] = hW[j]*dinv[j]^2 + b   (self-loop term initializes the accumulator)
__global__ __launch_bounds__(256) void selfloop_bias_kernel(const float* __restrict__ hW, const float* __restrict__ dinv,
                                                            const float* __restrict__ b, float* __restrict__ out, int n) {
    int idx = blockIdx.x * 256 + threadIdx.x;
    if (idx >= n * 32) return;
    int j = idx >> 5;
    int c4 = (idx & 31) * 4;
    float d = dinv[j];
    float s = d * d;
    float4 v = *(const float4*)&hW[(size_t)j * CH + c4];
    v.x = v.x * s + b[c4 + 0];
    v.y = v.y * s + b[c4 + 1];
    v.z = v.z * s + b[c4 + 2];
    v.w = v.w * s + b[c4 + 3];
    *(float4*)&out[(size_t)j * CH + c4] = v;
}

// one wave per edge: out[col] += hW[row] * dinv[row]*w*dinv[col]
__global__ __launch_bounds__(256) void edge_scatter_kernel(const float* __restrict__ hW, const int* __restrict__ rows,
                                                           const int* __restrict__ cols, const float* __restrict__ ew,
                                                           const float* __restrict__ dinv, float* __restrict__ out, int E) {
    int lane = threadIdx.x & 63;
    int w = blockIdx.x * 4 + (threadIdx.x >> 6);
    if (w >= E) return;
    int r = rows[w];
    int c = cols[w];
    float s = dinv[r] * ew[w] * dinv[c];
    float2 v = *(const float2*)&hW[(size_t)r * CH + lane * 2];
    unsafeAtomicAdd(&out[(size_t)c * CH + lane * 2 + 0], v.x * s);
    unsafeAtomicAdd(&out[(size_t)c * CH + lane * 2 + 1], v.y * s);
}

// GraphNorm (optionally ReLU) in place, from per-channel S1/S2
__global__ __launch_bounds__(256) void norm_kernel(float* __restrict__ h, const float* __restrict__ s1,
                                                   const float* __restrict__ s2, const float* __restrict__ gw,
                                                   const float* __restrict__ gb, const float* __restrict__ ga,
                                                   float inv_n, int n, int do_relu) {
    int idx = blockIdx.x * 256 + threadIdx.x;
    if (idx >= n * 32) return;
    int j = idx >> 5;
    int c4 = (idx & 31) * 4;
    float4 v = *(const float4*)&h[(size_t)j * CH + c4];
    float vv[4] = {v.x, v.y, v.z, v.w};
    float o[4];
#pragma unroll
    for (int i = 0; i < 4; ++i) {
        int c = c4 + i;
        float m = s1[c] * inv_n;
        float msq = s2[c] * inv_n;
        float a = ga[c];
        float var = msq + m * m * (a * a - 2.f * a);
        float r = rsqrtf(var + cEPS);
        float cv = vv[i] - a * m;
        float ov = gw[c] * cv * r + gb[c];
        if (do_relu) ov = fmaxf(ov, 0.f);
        o[i] = ov;
    }
    *(float4*)&h[(size_t)j * CH + c4] = make_float4(o[0], o[1], o[2], o[3]);
}

extern "C" void kernel_launch(void* const* d_in, const int* in_sizes, int n_in,
                              void* d_out, int out_size, void* d_ws, size_t ws_size,
                              hipStream_t stream) {
    const float* x    = (const float*)d_in[0];
    const float* res1 = (const float*)d_in[1];
    const float* res2 = (const float*)d_in[2];
    const float* ew1  = (const float*)d_in[3];
    const float* ew2  = (const float*)d_in[4];
    const float* W1   = (const float*)d_in[5];
    const float* b1   = (const float*)d_in[6];
    const float* W2   = (const float*)d_in[7];
    const float* b2   = (const float*)d_in[8];
    const float* g1w  = (const float*)d_in[9];
    const float* g1b  = (const float*)d_in[10];
    const float* g1a  = (const float*)d_in[11];
    const float* g2w  = (const float*)d_in[12];
    const float* g2b  = (const float*)d_in[13];
    const float* g2a  = (const float*)d_in[14];
    const int* ei1    = (const int*)d_in[15];
    const int* ei2    = (const int*)d_in[16];
    const int* perm1  = (const int*)d_in[17];
    const int* perm2  = (const int*)d_in[18];
    float* out = (float*)d_out;

    // workspace layout (floats)
    size_t NC0 = (size_t)cN0 * CH;  // 12.8M
    size_t NC1 = (size_t)cN1 * CH;  // 6.4M
    float* ws_f  = (float*)d_ws;
    float* upbuf = ws_f;                  // up1 (N1*C) then up2 (N0*C)
    float* hW1   = ws_f + NC0;            // N1*C
    float* h1    = ws_f + NC0 + NC1;      // N1*C (layer-1 accumulator / normalized h)
    float* hW2   = ws_f + NC0;            // N0*C (overlaps hW1+h1, both dead by then)
    float* deg   = ws_f + 2 * NC0;        // N0
    float* stats = deg + cN0;             // 1024 floats
    int*   inv   = (int*)(stats + 1024);  // N0 ints

    float* s1x = stats + 0;   float* s2x = stats + 128;  // x stats
    float* s1a = stats + 256; float* s2a = stats + 384;  // layer-1 GCN-out stats
    float* sh1 = stats + 512; float* sh2 = stats + 640;  // h1 colsum
    float* s1b = stats + 768; float* s2b = stats + 896;  // layer-2 GCN-out stats

    hipMemsetAsync(stats, 0, 1024 * sizeof(float), stream);

    // ---- layer 0: N2 -> N1 ----
    colstats_kernel<<<512, 256, 0, stream>>>(x, cN2, s1x, s2x);
    fill_inv_kernel<<<cdiv(cN1, 256), 256, 0, stream>>>(inv, cN1);
    scatter_inv_kernel<<<cdiv(cN2, 256), 256, 0, stream>>>(perm1, inv, cN2);
    unpool_kernel<<<cdiv(cN1 * 32, 256), 256, 0, stream>>>(x, inv, s1x, 1.f / cN2, res1, upbuf, cN1);

    hipMemsetAsync(deg, 0, (size_t)cN1 * sizeof(float), stream);
    edge_deg_kernel<<<cdiv(cE1, 256), 256, 0, stream>>>(ei1 + cE1, ew1, deg, cE1);
    dinv_kernel<<<cdiv(cN1, 256), 256, 0, stream>>>(deg, cN1);

    gemm128_kernel<<<cdiv(cN1, 32), 256, 0, stream>>>(upbuf, W1, hW1, cN1);
    selfloop_bias_kernel<<<cdiv(cN1 * 32, 256), 256, 0, stream>>>(hW1, deg, b1, h1, cN1);
    edge_scatter_kernel<<<cdiv(cE1, 4), 256, 0, stream>>>(hW1, ei1, ei1 + cE1, ew1, deg, h1, cE1);

    colstats_kernel<<<512, 256, 0, stream>>>(h1, cN1, s1a, s2a);
    norm_kernel<<<cdiv(cN1 * 32, 256), 256, 0, stream>>>(h1, s1a, s2a, g1w, g1b, g1a, 1.f / cN1, cN1, 1);
    colstats_kernel<<<512, 256, 0, stream>>>(h1, cN1, sh1, sh2);

    // ---- layer 1: N1 -> N0 ----
    fill_inv_kernel<<<cdiv(cN0, 256), 256, 0, stream>>>(inv, cN0);
    scatter_inv_kernel<<<cdiv(cN1, 256), 256, 0, stream>>>(perm2, inv, cN1);
    unpool_kernel<<<cdiv(cN0 * 32, 256), 256, 0, stream>>>(h1, inv, sh1, 1.f / cN1, res2, upbuf, cN0);

    hipMemsetAsync(deg, 0, (size_t)cN0 * sizeof(float), stream);
    edge_deg_kernel<<<cdiv(cE2, 256), 256, 0, stream>>>(ei2 + cE2, ew2, deg, cE2);
    dinv_kernel<<<cdiv(cN0, 256), 256, 0, stream>>>(deg, cN0);

    gemm128_kernel<<<cdiv(cN0, 32), 256, 0, stream>>>(upbuf, W2, hW2, cN0);
    selfloop_bias_kernel<<<cdiv(cN0 * 32, 256), 256, 0, stream>>>(hW2, deg, b2, out, cN0);
    edge_scatter_kernel<<<cdiv(cE2, 4), 256, 0, stream>>>(hW2, ei2, ei2 + cE2, ew2, deg, out, cE2);

    colstats_kernel<<<512, 256, 0, stream>>>(out, cN0, s1b, s2b);
    norm_kernel<<<cdiv(cN0 * 32, 256), 256, 0, stream>>>(out, s1b, s2b, g2w, g2b, g2a, 1.f / cN0, cN0, 0);
}

// Round 4
// 1690.660 us; speedup vs baseline: 1.8834x; 1.8834x over previous
//
#include <hip/hip_runtime.h>

#define CH 128
constexpr int cN2 = 25000, cN1 = 50000, cN0 = 100000;
constexpr int cE1 = 500000, cE2 = 1000000;
constexpr float cEPS = 1e-5f;

static inline int cdiv(int a, int b) { return (a + b - 1) / b; }

// per-channel sum and sum-of-squares over rows
__global__ __launch_bounds__(256) void colstats_kernel(const float* __restrict__ in, int n,
                                                       float* __restrict__ s1, float* __restrict__ s2) {
    int tid = threadIdx.x;
    int c = tid & 127;
    int h = tid >> 7;  // 0/1
    float a1 = 0.f, a2 = 0.f;
    for (int r = blockIdx.x * 2 + h; r < n; r += gridDim.x * 2) {
        float v = in[(size_t)r * CH + c];
        a1 += v;
        a2 += v * v;
    }
    __shared__ float l1[256], l2[256];
    l1[tid] = a1;
    l2[tid] = a2;
    __syncthreads();
    if (h == 0) {
        a1 += l1[tid + 128];
        a2 += l2[tid + 128];
        unsafeAtomicAdd(&s1[c], a1);
        unsafeAtomicAdd(&s2[c], a2);
    }
}

__global__ __launch_bounds__(256) void fill_inv_kernel(int* __restrict__ inv, int n) {
    int i = blockIdx.x * 256 + threadIdx.x;
    if (i < n) inv[i] = -1;
}

__global__ __launch_bounds__(256) void scatter_inv_kernel(const int* __restrict__ perm, int* __restrict__ inv, int m) {
    int i = blockIdx.x * 256 + threadIdx.x;
    if (i < m) inv[perm[i]] = i;
}

// out[j] = (inv[j]>=0 ? src[inv[j]] : colsum*inv_cnt) + res[j]
__global__ __launch_bounds__(256) void unpool_kernel(const float* __restrict__ src, const int* __restrict__ inv,
                                                     const float* __restrict__ colsum, float inv_cnt,
                                                     const float* __restrict__ res, float* __restrict__ out, int n) {
    int idx = blockIdx.x * 256 + threadIdx.x;
    if (idx >= n * 32) return;
    int j = idx >> 5;
    int c4 = (idx & 31) * 4;
    int iv = inv[j];
    float4 v;
    if (iv >= 0) {
        v = *(const float4*)&src[(size_t)iv * CH + c4];
    } else {
        v.x = colsum[c4 + 0] * inv_cnt;
        v.y = colsum[c4 + 1] * inv_cnt;
        v.z = colsum[c4 + 2] * inv_cnt;
        v.w = colsum[c4 + 3] * inv_cnt;
    }
    float rv = res[j];
    v.x += rv; v.y += rv; v.z += rv; v.w += rv;
    *(float4*)&out[(size_t)j * CH + c4] = v;
}

__global__ __launch_bounds__(256) void edge_deg_kernel(const int* __restrict__ col, const float* __restrict__ ew,
                                                       float* __restrict__ deg, int E) {
    int e = blockIdx.x * 256 + threadIdx.x;
    if (e < E) unsafeAtomicAdd(&deg[col[e]], ew[e]);
}

__global__ __launch_bounds__(256) void dinv_kernel(float* __restrict__ deg, int n) {
    int i = blockIdx.x * 256 + threadIdx.x;
    if (i < n) deg[i] = rsqrtf(deg[i] + 1.0f);  // self-loop weight 1 added analytically
}

// Out[n x 128] = A[n x 128] @ W[128 x 128], fp32, fused self-loop epilogue.
// W (64KB) + 32-row A tile (16KB) in LDS; 4 rows x 4 cols per thread; k-loop
// unrolled only 2x to keep VGPRs < 128 (round-1 version fully unrolled ->
// 256 VGPR + 1.4GB scratch spill traffic).
__global__ __launch_bounds__(256) void gemm128_fused_kernel(const float* __restrict__ A, const float* __restrict__ W,
                                                            const float* __restrict__ dinv, const float* __restrict__ bias,
                                                            float* __restrict__ hW, float* __restrict__ outinit, int n) {
    __shared__ float Ws[CH * CH];   // 64 KB
    __shared__ float As[32 * CH];   // 16 KB
    int tid = threadIdx.x;
    for (int i = tid * 4; i < CH * CH; i += 256 * 4)
        *(float4*)&Ws[i] = *(const float4*)&W[i];
    int rowbase = blockIdx.x * 32;
    for (int i = tid; i < 32 * 32; i += 256) {   // 32 rows x 32 float4 per row
        int r = i >> 5, c4 = (i & 31) * 4;
        int gr = min(rowbase + r, n - 1);
        *(float4*)&As[r * CH + c4] = *(const float4*)&A[(size_t)gr * CH + c4];
    }
    __syncthreads();

    int rg = (tid >> 5) * 4;   // 4 rows per thread-group
    int cc = (tid & 31) * 4;   // 4 cols per thread
    float acc[4][4] = {};
#pragma unroll 2
    for (int k = 0; k < CH; k += 4) {
        float4 a[4];
#pragma unroll
        for (int r = 0; r < 4; ++r) a[r] = *(const float4*)&As[(rg + r) * CH + k];
#pragma unroll
        for (int s = 0; s < 4; ++s) {
            float4 wv = *(const float4*)&Ws[(k + s) * CH + cc];
#pragma unroll
            for (int r = 0; r < 4; ++r) {
                float as = (s == 0) ? a[r].x : (s == 1) ? a[r].y : (s == 2) ? a[r].z : a[r].w;
                acc[r][0] += as * wv.x;
                acc[r][1] += as * wv.y;
                acc[r][2] += as * wv.z;
                acc[r][3] += as * wv.w;
            }
        }
    }
#pragma unroll
    for (int r = 0; r < 4; ++r) {
        int gr = rowbase + rg + r;
        if (gr < n) {
            float4 v = make_float4(acc[r][0], acc[r][1], acc[r][2], acc[r][3]);
            *(float4*)&hW[(size_t)gr * CH + cc] = v;
            float d = dinv[gr];
            float s = d * d;
            float4 o;
            o.x = v.x * s + bias[cc + 0];
            o.y = v.y * s + bias[cc + 1];
            o.z = v.z * s + bias[cc + 2];
            o.w = v.w * s + bias[cc + 3];
            *(float4*)&outinit[(size_t)gr * CH + cc] = o;
        }
    }
}

// one wave per edge: out[col] += hW[row] * dinv[row]*w*dinv[col]
__global__ __launch_bounds__(256) void edge_scatter_kernel(const float* __restrict__ hW, const int* __restrict__ rows,
                                                           const int* __restrict__ cols, const float* __restrict__ ew,
                                                           const float* __restrict__ dinv, float* __restrict__ out, int E) {
    int lane = threadIdx.x & 63;
    int w = blockIdx.x * 4 + (threadIdx.x >> 6);
    if (w >= E) return;
    int r = rows[w];
    int c = cols[w];
    float s = dinv[r] * ew[w] * dinv[c];
    float2 v = *(const float2*)&hW[(size_t)r * CH + lane * 2];
    unsafeAtomicAdd(&out[(size_t)c * CH + lane * 2 + 0], v.x * s);
    unsafeAtomicAdd(&out[(size_t)c * CH + lane * 2 + 1], v.y * s);
}

// GraphNorm (optionally ReLU) in place, from per-channel S1/S2
__global__ __launch_bounds__(256) void norm_kernel(float* __restrict__ h, const float* __restrict__ s1,
                                                   const float* __restrict__ s2, const float* __restrict__ gw,
                                                   const float* __restrict__ gb, const float* __restrict__ ga,
                                                   float inv_n, int n, int do_relu) {
    int idx = blockIdx.x * 256 + threadIdx.x;
    if (idx >= n * 32) return;
    int j = idx >> 5;
    int c4 = (idx & 31) * 4;
    float4 v = *(const float4*)&h[(size_t)j * CH + c4];
    float vv[4] = {v.x, v.y, v.z, v.w};
    float o[4];
#pragma unroll
    for (int i = 0; i < 4; ++i) {
        int c = c4 + i;
        float m = s1[c] * inv_n;
        float msq = s2[c] * inv_n;
        float a = ga[c];
        float var = msq + m * m * (a * a - 2.f * a);
        float r = rsqrtf(var + cEPS);
        float cv = vv[i] - a * m;
        float ov = gw[c] * cv * r + gb[c];
        if (do_relu) ov = fmaxf(ov, 0.f);
        o[i] = ov;
    }
    *(float4*)&h[(size_t)j * CH + c4] = make_float4(o[0], o[1], o[2], o[3]);
}

extern "C" void kernel_launch(void* const* d_in, const int* in_sizes, int n_in,
                              void* d_out, int out_size, void* d_ws, size_t ws_size,
                              hipStream_t stream) {
    const float* x    = (const float*)d_in[0];
    const float* res1 = (const float*)d_in[1];
    const float* res2 = (const float*)d_in[2];
    const float* ew1  = (const float*)d_in[3];
    const float* ew2  = (const float*)d_in[4];
    const float* W1   = (const float*)d_in[5];
    const float* b1   = (const float*)d_in[6];
    const float* W2   = (const float*)d_in[7];
    const float* b2   = (const float*)d_in[8];
    const float* g1w  = (const float*)d_in[9];
    const float* g1b  = (const float*)d_in[10];
    const float* g1a  = (const float*)d_in[11];
    const float* g2w  = (const float*)d_in[12];
    const float* g2b  = (const float*)d_in[13];
    const float* g2a  = (const float*)d_in[14];
    const int* ei1    = (const int*)d_in[15];
    const int* ei2    = (const int*)d_in[16];
    const int* perm1  = (const int*)d_in[17];
    const int* perm2  = (const int*)d_in[18];
    float* out = (float*)d_out;

    // workspace layout (floats)
    size_t NC0 = (size_t)cN0 * CH;  // 12.8M
    size_t NC1 = (size_t)cN1 * CH;  // 6.4M
    float* ws_f  = (float*)d_ws;
    float* upbuf = ws_f;                  // up1 (N1*C) then up2 (N0*C)
    float* hW1   = ws_f + NC0;            // N1*C
    float* h1    = ws_f + NC0 + NC1;      // N1*C (layer-1 accumulator / normalized h)
    float* hW2   = ws_f + NC0;            // N0*C (overlaps hW1+h1, both dead by then)
    float* deg   = ws_f + 2 * NC0;        // N0
    float* stats = deg + cN0;             // 1024 floats
    int*   inv   = (int*)(stats + 1024);  // N0 ints

    float* s1x = stats + 0;   float* s2x = stats + 128;  // x stats
    float* s1a = stats + 256; float* s2a = stats + 384;  // layer-1 GCN-out stats
    float* sh1 = stats + 512; float* sh2 = stats + 640;  // h1 colsum
    float* s1b = stats + 768; float* s2b = stats + 896;  // layer-2 GCN-out stats

    hipMemsetAsync(stats, 0, 1024 * sizeof(float), stream);

    // ---- layer 0: N2 -> N1 ----
    colstats_kernel<<<512, 256, 0, stream>>>(x, cN2, s1x, s2x);
    fill_inv_kernel<<<cdiv(cN1, 256), 256, 0, stream>>>(inv, cN1);
    scatter_inv_kernel<<<cdiv(cN2, 256), 256, 0, stream>>>(perm1, inv, cN2);
    unpool_kernel<<<cdiv(cN1 * 32, 256), 256, 0, stream>>>(x, inv, s1x, 1.f / cN2, res1, upbuf, cN1);

    hipMemsetAsync(deg, 0, (size_t)cN1 * sizeof(float), stream);
    edge_deg_kernel<<<cdiv(cE1, 256), 256, 0, stream>>>(ei1 + cE1, ew1, deg, cE1);
    dinv_kernel<<<cdiv(cN1, 256), 256, 0, stream>>>(deg, cN1);

    gemm128_fused_kernel<<<cdiv(cN1, 32), 256, 0, stream>>>(upbuf, W1, deg, b1, hW1, h1, cN1);
    edge_scatter_kernel<<<cdiv(cE1, 4), 256, 0, stream>>>(hW1, ei1, ei1 + cE1, ew1, deg, h1, cE1);

    colstats_kernel<<<512, 256, 0, stream>>>(h1, cN1, s1a, s2a);
    norm_kernel<<<cdiv(cN1 * 32, 256), 256, 0, stream>>>(h1, s1a, s2a, g1w, g1b, g1a, 1.f / cN1, cN1, 1);
    colstats_kernel<<<512, 256, 0, stream>>>(h1, cN1, sh1, sh2);

    // ---- layer 1: N1 -> N0 ----
    fill_inv_kernel<<<cdiv(cN0, 256), 256, 0, stream>>>(inv, cN0);
    scatter_inv_kernel<<<cdiv(cN1, 256), 256, 0, stream>>>(perm2, inv, cN1);
    unpool_kernel<<<cdiv(cN0 * 32, 256), 256, 0, stream>>>(h1, inv, sh1, 1.f / cN1, res2, upbuf, cN0);

    hipMemsetAsync(deg, 0, (size_t)cN0 * sizeof(float), stream);
    edge_deg_kernel<<<cdiv(cE2, 256), 256, 0, stream>>>(ei2 + cE2, ew2, deg, cE2);
    dinv_kernel<<<cdiv(cN0, 256), 256, 0, stream>>>(deg, cN0);

    gemm128_fused_kernel<<<cdiv(cN0, 32), 256, 0, stream>>>(upbuf, W2, deg, b2, hW2, out, cN0);
    edge_scatter_kernel<<<cdiv(cE2, 4), 256, 0, stream>>>(hW2, ei2, ei2 + cE2, ew2, deg, out, cE2);

    colstats_kernel<<<512, 256, 0, stream>>>(out, cN0, s1b, s2b);
    norm_kernel<<<cdiv(cN0 * 32, 256), 256, 0, stream>>>(out, s1b, s2b, g2w, g2b, g2a, 1.f / cN0, cN0, 0);
}

// Round 9
// 1101.081 us; speedup vs baseline: 2.8919x; 1.5355x over previous
//
#include <hip/hip_runtime.h>

#define CH 128
constexpr int cN2 = 25000, cN1 = 50000, cN0 = 100000;
constexpr int cE1 = 500000, cE2 = 1000000;
constexpr float cEPS = 1e-5f;

static inline int cdiv(int a, int b) { return (a + b - 1) / b; }

// per-channel sum and sum-of-squares over rows
__global__ __launch_bounds__(256) void colstats_kernel(const float* __restrict__ in, int n,
                                                       float* __restrict__ s1, float* __restrict__ s2) {
    int tid = threadIdx.x;
    int c = tid & 127;
    int h = tid >> 7;  // 0/1
    float a1 = 0.f, a2 = 0.f;
    for (int r = blockIdx.x * 2 + h; r < n; r += gridDim.x * 2) {
        float v = in[(size_t)r * CH + c];
        a1 += v;
        a2 += v * v;
    }
    __shared__ float l1[256], l2[256];
    l1[tid] = a1;
    l2[tid] = a2;
    __syncthreads();
    if (h == 0) {
        a1 += l1[tid + 128];
        a2 += l2[tid + 128];
        unsafeAtomicAdd(&s1[c], a1);
        unsafeAtomicAdd(&s2[c], a2);
    }
}

__global__ __launch_bounds__(256) void fill_inv_kernel(int* __restrict__ inv, int n) {
    int i = blockIdx.x * 256 + threadIdx.x;
    if (i < n) inv[i] = -1;
}

__global__ __launch_bounds__(256) void scatter_inv_kernel(const int* __restrict__ perm, int* __restrict__ inv, int m) {
    int i = blockIdx.x * 256 + threadIdx.x;
    if (i < m) inv[perm[i]] = i;
}

// out[j] = (inv[j]>=0 ? src[inv[j]] : colsum*inv_cnt) + res[j]
__global__ __launch_bounds__(256) void unpool_kernel(const float* __restrict__ src, const int* __restrict__ inv,
                                                     const float* __restrict__ colsum, float inv_cnt,
                                                     const float* __restrict__ res, float* __restrict__ out, int n) {
    int idx = blockIdx.x * 256 + threadIdx.x;
    if (idx >= n * 32) return;
    int j = idx >> 5;
    int c4 = (idx & 31) * 4;
    int iv = inv[j];
    float4 v;
    if (iv >= 0) {
        v = *(const float4*)&src[(size_t)iv * CH + c4];
    } else {
        v.x = colsum[c4 + 0] * inv_cnt;
        v.y = colsum[c4 + 1] * inv_cnt;
        v.z = colsum[c4 + 2] * inv_cnt;
        v.w = colsum[c4 + 3] * inv_cnt;
    }
    float rv = res[j];
    v.x += rv; v.y += rv; v.z += rv; v.w += rv;
    *(float4*)&out[(size_t)j * CH + c4] = v;
}

__global__ __launch_bounds__(256) void edge_deg_kernel(const int* __restrict__ col, const float* __restrict__ ew,
                                                       float* __restrict__ deg, int E) {
    int e = blockIdx.x * 256 + threadIdx.x;
    if (e < E) unsafeAtomicAdd(&deg[col[e]], ew[e]);
}

__global__ __launch_bounds__(256) void dinv_kernel(float* __restrict__ deg, int n) {
    int i = blockIdx.x * 256 + threadIdx.x;
    if (i < n) deg[i] = rsqrtf(deg[i] + 1.0f);  // self-loop weight 1 added analytically
}

// --- CSR build: histogram -> exclusive scan -> cursor scatter ---
__global__ __launch_bounds__(256) void edge_hist_kernel(const int* __restrict__ col, int* __restrict__ hist, int E) {
    int e = blockIdx.x * 256 + threadIdx.x;
    if (e < E) atomicAdd(&hist[col[e]], 1);
}

// single-dispatch exclusive scan: per-thread serial chunk + one 1024-wide Hillis-Steele.
// Writes both off[] and a second copy cursor[] (used by csr_scatter's atomic cursors).
__global__ __launch_bounds__(1024) void exscan_kernel(const int* __restrict__ cnt, int* __restrict__ off,
                                                      int* __restrict__ cursor, int n) {
    __shared__ int lds[1024];
    int tid = threadIdx.x;
    int chunk = (n + 1023) / 1024;
    int s = tid * chunk;
    int e = min(s + chunk, n);
    int sum = 0;
    for (int i = s; i < e; ++i) sum += cnt[i];
    lds[tid] = sum;
    __syncthreads();
    for (int ofs = 1; ofs < 1024; ofs <<= 1) {
        int t = (tid >= ofs) ? lds[tid - ofs] : 0;
        __syncthreads();
        lds[tid] += t;
        __syncthreads();
    }
    int run = lds[tid] - sum;  // exclusive prefix for this chunk
    for (int i = s; i < e; ++i) {
        off[i] = run;
        cursor[i] = run;
        run += cnt[i];
    }
    if (tid == 1023) off[n] = lds[1023];
}

// scatter (row, dinv[r]*w*dinv[c]) into CSR buckets via atomic cursor
__global__ __launch_bounds__(256) void csr_scatter_kernel(const int* __restrict__ rows, const int* __restrict__ cols,
                                                          const float* __restrict__ ew, const float* __restrict__ dinv,
                                                          int* __restrict__ cursor, int* __restrict__ csr_row,
                                                          float* __restrict__ csr_val, int E) {
    int e = blockIdx.x * 256 + threadIdx.x;
    if (e >= E) return;
    int r = rows[e];
    int c = cols[e];
    int p = atomicAdd(&cursor[c], 1);
    csr_row[p] = r;
    csr_val[p] = dinv[r] * ew[e] * dinv[c];
}

// Out[n x 128] = A[n x 128] @ W[128 x 128], fp32, fused self-loop epilogue.
// W (64KB) + 32-row A tile (16KB) in LDS; 4 rows x 4 cols per thread; k-loop
// unrolled only 2x to keep VGPRs < 128 (round-1 version fully unrolled ->
// 256 VGPR + 1.4GB scratch spill traffic).
__global__ __launch_bounds__(256) void gemm128_fused_kernel(const float* __restrict__ A, const float* __restrict__ W,
                                                            const float* __restrict__ dinv, const float* __restrict__ bias,
                                                            float* __restrict__ hW, float* __restrict__ outinit, int n) {
    __shared__ float Ws[CH * CH];   // 64 KB
    __shared__ float As[32 * CH];   // 16 KB
    int tid = threadIdx.x;
    for (int i = tid * 4; i < CH * CH; i += 256 * 4)
        *(float4*)&Ws[i] = *(const float4*)&W[i];
    int rowbase = blockIdx.x * 32;
    for (int i = tid; i < 32 * 32; i += 256) {   // 32 rows x 32 float4 per row
        int r = i >> 5, c4 = (i & 31) * 4;
        int gr = min(rowbase + r, n - 1);
        *(float4*)&As[r * CH + c4] = *(const float4*)&A[(size_t)gr * CH + c4];
    }
    __syncthreads();

    int rg = (tid >> 5) * 4;   // 4 rows per thread-group
    int cc = (tid & 31) * 4;   // 4 cols per thread
    float acc[4][4] = {};
#pragma unroll 2
    for (int k = 0; k < CH; k += 4) {
        float4 a[4];
#pragma unroll
        for (int r = 0; r < 4; ++r) a[r] = *(const float4*)&As[(rg + r) * CH + k];
#pragma unroll
        for (int s = 0; s < 4; ++s) {
            float4 wv = *(const float4*)&Ws[(k + s) * CH + cc];
#pragma unroll
            for (int r = 0; r < 4; ++r) {
                float as = (s == 0) ? a[r].x : (s == 1) ? a[r].y : (s == 2) ? a[r].z : a[r].w;
                acc[r][0] += as * wv.x;
                acc[r][1] += as * wv.y;
                acc[r][2] += as * wv.z;
                acc[r][3] += as * wv.w;
            }
        }
    }
#pragma unroll
    for (int r = 0; r < 4; ++r) {
        int gr = rowbase + rg + r;
        if (gr < n) {
            float4 v = make_float4(acc[r][0], acc[r][1], acc[r][2], acc[r][3]);
            *(float4*)&hW[(size_t)gr * CH + cc] = v;
            float d = dinv[gr];
            float s = d * d;
            float4 o;
            o.x = v.x * s + bias[cc + 0];
            o.y = v.y * s + bias[cc + 1];
            o.z = v.z * s + bias[cc + 2];
            o.w = v.w * s + bias[cc + 3];
            *(float4*)&outinit[(size_t)gr * CH + cc] = o;
        }
    }
}

// CSR gather: one wave per node, float2 per lane, out[c] += sum val*hW[row].
// Replaces the atomic edge scatter (r4: 815us E2, 157G atomics/s L2-bound).
__global__ __launch_bounds__(256) void gather_kernel(const float* __restrict__ hW, const int* __restrict__ off,
                                                     const int* __restrict__ csr_row, const float* __restrict__ csr_val,
                                                     float* __restrict__ out, int n) {
    int lane = threadIdx.x & 63;
    int node = blockIdx.x * 4 + (threadIdx.x >> 6);
    if (node >= n) return;
    int s = off[node], e = off[node + 1];
    float ax = 0.f, ay = 0.f;
    int i = s;
    for (; i + 1 < e; i += 2) {
        int r0 = csr_row[i], r1 = csr_row[i + 1];
        float v0 = csr_val[i], v1 = csr_val[i + 1];
        float2 h0 = *(const float2*)&hW[(size_t)r0 * CH + lane * 2];
        float2 h1 = *(const float2*)&hW[(size_t)r1 * CH + lane * 2];
        ax += v0 * h0.x + v1 * h1.x;
        ay += v0 * h0.y + v1 * h1.y;
    }
    if (i < e) {
        int r0 = csr_row[i];
        float v0 = csr_val[i];
        float2 h0 = *(const float2*)&hW[(size_t)r0 * CH + lane * 2];
        ax += v0 * h0.x;
        ay += v0 * h0.y;
    }
    float2 o = *(float2*)&out[(size_t)node * CH + lane * 2];  // self-loop + bias init from gemm epilogue
    o.x += ax;
    o.y += ay;
    *(float2*)&out[(size_t)node * CH + lane * 2] = o;
}

// GraphNorm (optionally ReLU) in place, from per-channel S1/S2
__global__ __launch_bounds__(256) void norm_kernel(float* __restrict__ h, const float* __restrict__ s1,
                                                   const float* __restrict__ s2, const float* __restrict__ gw,
                                                   const float* __restrict__ gb, const float* __restrict__ ga,
                                                   float inv_n, int n, int do_relu) {
    int idx = blockIdx.x * 256 + threadIdx.x;
    if (idx >= n * 32) return;
    int j = idx >> 5;
    int c4 = (idx & 31) * 4;
    float4 v = *(const float4*)&h[(size_t)j * CH + c4];
    float vv[4] = {v.x, v.y, v.z, v.w};
    float o[4];
#pragma unroll
    for (int i = 0; i < 4; ++i) {
        int c = c4 + i;
        float m = s1[c] * inv_n;
        float msq = s2[c] * inv_n;
        float a = ga[c];
        float var = msq + m * m * (a * a - 2.f * a);
        float r = rsqrtf(var + cEPS);
        float cv = vv[i] - a * m;
        float ov = gw[c] * cv * r + gb[c];
        if (do_relu) ov = fmaxf(ov, 0.f);
        o[i] = ov;
    }
    *(float4*)&h[(size_t)j * CH + c4] = make_float4(o[0], o[1], o[2], o[3]);
}

extern "C" void kernel_launch(void* const* d_in, const int* in_sizes, int n_in,
                              void* d_out, int out_size, void* d_ws, size_t ws_size,
                              hipStream_t stream) {
    const float* x    = (const float*)d_in[0];
    const float* res1 = (const float*)d_in[1];
    const float* res2 = (const float*)d_in[2];
    const float* ew1  = (const float*)d_in[3];
    const float* ew2  = (const float*)d_in[4];
    const float* W1   = (const float*)d_in[5];
    const float* b1   = (const float*)d_in[6];
    const float* W2   = (const float*)d_in[7];
    const float* b2   = (const float*)d_in[8];
    const float* g1w  = (const float*)d_in[9];
    const float* g1b  = (const float*)d_in[10];
    const float* g1a  = (const float*)d_in[11];
    const float* g2w  = (const float*)d_in[12];
    const float* g2b  = (const float*)d_in[13];
    const float* g2a  = (const float*)d_in[14];
    const int* ei1    = (const int*)d_in[15];
    const int* ei2    = (const int*)d_in[16];
    const int* perm1  = (const int*)d_in[17];
    const int* perm2  = (const int*)d_in[18];
    float* out = (float*)d_out;

    // workspace layout (floats). ~112 MB total.
    size_t NC0 = (size_t)cN0 * CH;  // 12.8M
    size_t NC1 = (size_t)cN1 * CH;  // 6.4M
    float* ws_f  = (float*)d_ws;
    float* upbuf = ws_f;                  // up1 (N1*C) then up2 (N0*C)
    float* hW1   = ws_f + NC0;            // N1*C
    float* h1    = ws_f + NC0 + NC1;      // N1*C (layer-1 accumulator / normalized h)
    float* hW2   = ws_f + NC0;            // N0*C (overlaps hW1+h1, both dead by then)
    float* deg   = ws_f + 2 * NC0;        // N0
    float* stats = deg + cN0;             // 1024 floats
    int*   inv   = (int*)(stats + 1024);  // N0 ints
    int*   hist  = inv + cN0;             // N0 ints (CSR cursor)
    int*   off   = hist + cN0;            // N0+1 ints
    int*   csr_row = off + cN0 + 1;       // E2 ints
    float* csr_val = (float*)(csr_row + cE2);  // E2 floats

    float* s1x = stats + 0;   float* s2x = stats + 128;  // x stats
    float* s1a = stats + 256; float* s2a = stats + 384;  // layer-1 GCN-out stats
    float* sh1 = stats + 512; float* sh2 = stats + 640;  // h1 colsum
    float* s1b = stats + 768; float* s2b = stats + 896;  // layer-2 GCN-out stats

    hipMemsetAsync(stats, 0, 1024 * sizeof(float), stream);

    // ---- layer 0: N2 -> N1 ----
    colstats_kernel<<<512, 256, 0, stream>>>(x, cN2, s1x, s2x);
    fill_inv_kernel<<<cdiv(cN1, 256), 256, 0, stream>>>(inv, cN1);
    scatter_inv_kernel<<<cdiv(cN2, 256), 256, 0, stream>>>(perm1, inv, cN2);
    unpool_kernel<<<cdiv(cN1 * 32, 256), 256, 0, stream>>>(x, inv, s1x, 1.f / cN2, res1, upbuf, cN1);

    hipMemsetAsync(deg, 0, (size_t)cN1 * sizeof(float), stream);
    edge_deg_kernel<<<cdiv(cE1, 256), 256, 0, stream>>>(ei1 + cE1, ew1, deg, cE1);
    dinv_kernel<<<cdiv(cN1, 256), 256, 0, stream>>>(deg, cN1);

    hipMemsetAsync(hist, 0, (size_t)cN1 * sizeof(int), stream);
    edge_hist_kernel<<<cdiv(cE1, 256), 256, 0, stream>>>(ei1 + cE1, hist, cE1);
    exscan_kernel<<<1, 1024, 0, stream>>>(hist, off, hist, cN1);  // hist becomes cursor
    csr_scatter_kernel<<<cdiv(cE1, 256), 256, 0, stream>>>(ei1, ei1 + cE1, ew1, deg, hist, csr_row, csr_val, cE1);

    gemm128_fused_kernel<<<cdiv(cN1, 32), 256, 0, stream>>>(upbuf, W1, deg, b1, hW1, h1, cN1);
    gather_kernel<<<cdiv(cN1, 4), 256, 0, stream>>>(hW1, off, csr_row, csr_val, h1, cN1);

    colstats_kernel<<<512, 256, 0, stream>>>(h1, cN1, s1a, s2a);
    norm_kernel<<<cdiv(cN1 * 32, 256), 256, 0, stream>>>(h1, s1a, s2a, g1w, g1b, g1a, 1.f / cN1, cN1, 1);
    colstats_kernel<<<512, 256, 0, stream>>>(h1, cN1, sh1, sh2);

    // ---- layer 1: N1 -> N0 ----
    fill_inv_kernel<<<cdiv(cN0, 256), 256, 0, stream>>>(inv, cN0);
    scatter_inv_kernel<<<cdiv(cN1, 256), 256, 0, stream>>>(perm2, inv, cN1);
    unpool_kernel<<<cdiv(cN0 * 32, 256), 256, 0, stream>>>(h1, inv, sh1, 1.f / cN1, res2, upbuf, cN0);

    hipMemsetAsync(deg, 0, (size_t)cN0 * sizeof(float), stream);
    edge_deg_kernel<<<cdiv(cE2, 256), 256, 0, stream>>>(ei2 + cE2, ew2, deg, cE2);
    dinv_kernel<<<cdiv(cN0, 256), 256, 0, stream>>>(deg, cN0);

    hipMemsetAsync(hist, 0, (size_t)cN0 * sizeof(int), stream);
    edge_hist_kernel<<<cdiv(cE2, 256), 256, 0, stream>>>(ei2 + cE2, hist, cE2);
    exscan_kernel<<<1, 1024, 0, stream>>>(hist, off, hist, cN0);  // hist becomes cursor
    csr_scatter_kernel<<<cdiv(cE2, 256), 256, 0, stream>>>(ei2, ei2 + cE2, ew2, deg, hist, csr_row, csr_val, cE2);

    gemm128_fused_kernel<<<cdiv(cN0, 32), 256, 0, stream>>>(upbuf, W2, deg, b2, hW2, out, cN0);
    gather_kernel<<<cdiv(cN0, 4), 256, 0, stream>>>(hW2, off, csr_row, csr_val, out, cN0);

    colstats_kernel<<<512, 256, 0, stream>>>(out, cN0, s1b, s2b);
    norm_kernel<<<cdiv(cN0 * 32, 256), 256, 0, stream>>>(out, s1b, s2b, g2w, g2b, g2a, 1.f / cN0, cN0, 0);
}

// Round 10
// 791.090 us; speedup vs baseline: 4.0251x; 1.3919x over previous
//
#include <hip/hip_runtime.h>

#define CH 128
constexpr int cN2 = 25000, cN1 = 50000, cN0 = 100000;
constexpr int cE1 = 500000, cE2 = 1000000;
constexpr float cEPS = 1e-5f;

static inline int cdiv(int a, int b) { return (a + b - 1) / b; }

// per-channel sum and sum-of-squares over rows
__global__ __launch_bounds__(256) void colstats_kernel(const float* __restrict__ in, int n,
                                                       float* __restrict__ s1, float* __restrict__ s2) {
    int tid = threadIdx.x;
    int c = tid & 127;
    int h = tid >> 7;  // 0/1
    float a1 = 0.f, a2 = 0.f;
    for (int r = blockIdx.x * 2 + h; r < n; r += gridDim.x * 2) {
        float v = in[(size_t)r * CH + c];
        a1 += v;
        a2 += v * v;
    }
    __shared__ float l1[256], l2[256];
    l1[tid] = a1;
    l2[tid] = a2;
    __syncthreads();
    if (h == 0) {
        a1 += l1[tid + 128];
        a2 += l2[tid + 128];
        unsafeAtomicAdd(&s1[c], a1);
        unsafeAtomicAdd(&s2[c], a2);
    }
}

__global__ __launch_bounds__(256) void fill_inv_kernel(int* __restrict__ inv, int n) {
    int i = blockIdx.x * 256 + threadIdx.x;
    if (i < n) inv[i] = -1;
}

__global__ __launch_bounds__(256) void scatter_inv_kernel(const int* __restrict__ perm, int* __restrict__ inv, int m) {
    int i = blockIdx.x * 256 + threadIdx.x;
    if (i < m) inv[perm[i]] = i;
}

// out[j] = (inv[j]>=0 ? src[inv[j]] : colsum*inv_cnt) + res[j]
__global__ __launch_bounds__(256) void unpool_kernel(const float* __restrict__ src, const int* __restrict__ inv,
                                                     const float* __restrict__ colsum, float inv_cnt,
                                                     const float* __restrict__ res, float* __restrict__ out, int n) {
    int idx = blockIdx.x * 256 + threadIdx.x;
    if (idx >= n * 32) return;
    int j = idx >> 5;
    int c4 = (idx & 31) * 4;
    int iv = inv[j];
    float4 v;
    if (iv >= 0) {
        v = *(const float4*)&src[(size_t)iv * CH + c4];
    } else {
        v.x = colsum[c4 + 0] * inv_cnt;
        v.y = colsum[c4 + 1] * inv_cnt;
        v.z = colsum[c4 + 2] * inv_cnt;
        v.w = colsum[c4 + 3] * inv_cnt;
    }
    float rv = res[j];
    v.x += rv; v.y += rv; v.z += rv; v.w += rv;
    *(float4*)&out[(size_t)j * CH + c4] = v;
}

// fused: deg[c] += w  and  hist[c] += 1  (one edge-col pass instead of two)
__global__ __launch_bounds__(256) void edge_deg_hist_kernel(const int* __restrict__ col, const float* __restrict__ ew,
                                                            float* __restrict__ deg, int* __restrict__ hist, int E) {
    int e = blockIdx.x * 256 + threadIdx.x;
    if (e < E) {
        int c = col[e];
        unsafeAtomicAdd(&deg[c], ew[e]);
        atomicAdd(&hist[c], 1);
    }
}

__global__ __launch_bounds__(256) void dinv_kernel(float* __restrict__ deg, int n) {
    int i = blockIdx.x * 256 + threadIdx.x;
    if (i < n) deg[i] = rsqrtf(deg[i] + 1.0f);  // self-loop weight 1 added analytically
}

// --- hierarchical exclusive scan (r9: single-block exscan was 227us, 0.15% occupancy,
//     latency-bound on 1 CU; 3-dispatch coalesced version ~15us/layer) ---
constexpr int SCAN_ITEMS = 1024;  // items per block, 4 per thread

// phase 1: per-block sums
__global__ __launch_bounds__(256) void scan_reduce_kernel(const int* __restrict__ cnt, int* __restrict__ bsum, int n) {
    __shared__ int lds[256];
    int base = blockIdx.x * SCAN_ITEMS;
    int sum = 0;
    for (int i = threadIdx.x; i < SCAN_ITEMS; i += 256) {
        int idx = base + i;
        sum += (idx < n) ? cnt[idx] : 0;
    }
    lds[threadIdx.x] = sum;
    __syncthreads();
    for (int ofs = 128; ofs > 0; ofs >>= 1) {
        if (threadIdx.x < ofs) lds[threadIdx.x] += lds[threadIdx.x + ofs];
        __syncthreads();
    }
    if (threadIdx.x == 0) bsum[blockIdx.x] = lds[0];
}

// phase 2: one block exclusive-scans the block sums (nb <= 1024)
__global__ __launch_bounds__(1024) void scan_blocksums_kernel(int* __restrict__ bsum, int nb) {
    __shared__ int lds[1024];
    int tid = threadIdx.x;
    int v = (tid < nb) ? bsum[tid] : 0;
    lds[tid] = v;
    __syncthreads();
    for (int ofs = 1; ofs < 1024; ofs <<= 1) {
        int t = (tid >= ofs) ? lds[tid - ofs] : 0;
        __syncthreads();
        lds[tid] += t;
        __syncthreads();
    }
    if (tid < nb) bsum[tid] = lds[tid] - v;  // exclusive
}

// phase 3: rescan chunk, add block offset, write off[] and cursor[] coalesced
__global__ __launch_bounds__(256) void scan_apply_kernel(const int* __restrict__ cnt, const int* __restrict__ bsum,
                                                         int* __restrict__ off, int* __restrict__ cursor, int n) {
    __shared__ int lds[256];
    int tid = threadIdx.x;
    int idx0 = blockIdx.x * SCAN_ITEMS + tid * 4;
    int v[4];
#pragma unroll
    for (int j = 0; j < 4; ++j) {
        int idx = idx0 + j;
        v[j] = (idx < n) ? cnt[idx] : 0;
    }
    int tsum = v[0] + v[1] + v[2] + v[3];
    lds[tid] = tsum;
    __syncthreads();
    for (int ofs = 1; ofs < 256; ofs <<= 1) {
        int t = (tid >= ofs) ? lds[tid - ofs] : 0;
        __syncthreads();
        lds[tid] += t;
        __syncthreads();
    }
    int run = bsum[blockIdx.x] + lds[tid] - tsum;  // exclusive prefix for this thread's 4 items
#pragma unroll
    for (int j = 0; j < 4; ++j) {
        int idx = idx0 + j;
        if (idx < n) {
            off[idx] = run;
            cursor[idx] = run;
        }
        run += v[j];
    }
    if (blockIdx.x == gridDim.x - 1 && tid == 255) off[n] = run;  // total (pad items are 0)
}

// scatter (row, dinv[r]*w*dinv[c]) into CSR buckets via atomic cursor
__global__ __launch_bounds__(256) void csr_scatter_kernel(const int* __restrict__ rows, const int* __restrict__ cols,
                                                          const float* __restrict__ ew, const float* __restrict__ dinv,
                                                          int* __restrict__ cursor, int* __restrict__ csr_row,
                                                          float* __restrict__ csr_val, int E) {
    int e = blockIdx.x * 256 + threadIdx.x;
    if (e >= E) return;
    int r = rows[e];
    int c = cols[e];
    int p = atomicAdd(&cursor[c], 1);
    csr_row[p] = r;
    csr_val[p] = dinv[r] * ew[e] * dinv[c];
}

// Out[n x 128] = A[n x 128] @ W[128 x 128], fp32, fused self-loop epilogue.
// W (64KB) + 32-row A tile (16KB) in LDS; 4 rows x 4 cols per thread; k-loop
// unrolled only 2x to keep VGPRs < 128.
__global__ __launch_bounds__(256) void gemm128_fused_kernel(const float* __restrict__ A, const float* __restrict__ W,
                                                            const float* __restrict__ dinv, const float* __restrict__ bias,
                                                            float* __restrict__ hW, float* __restrict__ outinit, int n) {
    __shared__ float Ws[CH * CH];   // 64 KB
    __shared__ float As[32 * CH];   // 16 KB
    int tid = threadIdx.x;
    for (int i = tid * 4; i < CH * CH; i += 256 * 4)
        *(float4*)&Ws[i] = *(const float4*)&W[i];
    int rowbase = blockIdx.x * 32;
    for (int i = tid; i < 32 * 32; i += 256) {   // 32 rows x 32 float4 per row
        int r = i >> 5, c4 = (i & 31) * 4;
        int gr = min(rowbase + r, n - 1);
        *(float4*)&As[r * CH + c4] = *(const float4*)&A[(size_t)gr * CH + c4];
    }
    __syncthreads();

    int rg = (tid >> 5) * 4;   // 4 rows per thread-group
    int cc = (tid & 31) * 4;   // 4 cols per thread
    float acc[4][4] = {};
#pragma unroll 2
    for (int k = 0; k < CH; k += 4) {
        float4 a[4];
#pragma unroll
        for (int r = 0; r < 4; ++r) a[r] = *(const float4*)&As[(rg + r) * CH + k];
#pragma unroll
        for (int s = 0; s < 4; ++s) {
            float4 wv = *(const float4*)&Ws[(k + s) * CH + cc];
#pragma unroll
            for (int r = 0; r < 4; ++r) {
                float as = (s == 0) ? a[r].x : (s == 1) ? a[r].y : (s == 2) ? a[r].z : a[r].w;
                acc[r][0] += as * wv.x;
                acc[r][1] += as * wv.y;
                acc[r][2] += as * wv.z;
                acc[r][3] += as * wv.w;
            }
        }
    }
#pragma unroll
    for (int r = 0; r < 4; ++r) {
        int gr = rowbase + rg + r;
        if (gr < n) {
            float4 v = make_float4(acc[r][0], acc[r][1], acc[r][2], acc[r][3]);
            *(float4*)&hW[(size_t)gr * CH + cc] = v;
            float d = dinv[gr];
            float s = d * d;
            float4 o;
            o.x = v.x * s + bias[cc + 0];
            o.y = v.y * s + bias[cc + 1];
            o.z = v.z * s + bias[cc + 2];
            o.w = v.w * s + bias[cc + 3];
            *(float4*)&outinit[(size_t)gr * CH + cc] = o;
        }
    }
}

// CSR gather: one wave per node, float2 per lane, out[c] += sum val*hW[row].
__global__ __launch_bounds__(256) void gather_kernel(const float* __restrict__ hW, const int* __restrict__ off,
                                                     const int* __restrict__ csr_row, const float* __restrict__ csr_val,
                                                     float* __restrict__ out, int n) {
    int lane = threadIdx.x & 63;
    int node = blockIdx.x * 4 + (threadIdx.x >> 6);
    if (node >= n) return;
    int s = off[node], e = off[node + 1];
    float ax = 0.f, ay = 0.f;
    int i = s;
    for (; i + 1 < e; i += 2) {
        int r0 = csr_row[i], r1 = csr_row[i + 1];
        float v0 = csr_val[i], v1 = csr_val[i + 1];
        float2 h0 = *(const float2*)&hW[(size_t)r0 * CH + lane * 2];
        float2 h1 = *(const float2*)&hW[(size_t)r1 * CH + lane * 2];
        ax += v0 * h0.x + v1 * h1.x;
        ay += v0 * h0.y + v1 * h1.y;
    }
    if (i < e) {
        int r0 = csr_row[i];
        float v0 = csr_val[i];
        float2 h0 = *(const float2*)&hW[(size_t)r0 * CH + lane * 2];
        ax += v0 * h0.x;
        ay += v0 * h0.y;
    }
    float2 o = *(float2*)&out[(size_t)node * CH + lane * 2];  // self-loop + bias init from gemm epilogue
    o.x += ax;
    o.y += ay;
    *(float2*)&out[(size_t)node * CH + lane * 2] = o;
}

// GraphNorm (optionally ReLU) in place, from per-channel S1/S2
__global__ __launch_bounds__(256) void norm_kernel(float* __restrict__ h, const float* __restrict__ s1,
                                                   const float* __restrict__ s2, const float* __restrict__ gw,
                                                   const float* __restrict__ gb, const float* __restrict__ ga,
                                                   float inv_n, int n, int do_relu) {
    int idx = blockIdx.x * 256 + threadIdx.x;
    if (idx >= n * 32) return;
    int j = idx >> 5;
    int c4 = (idx & 31) * 4;
    float4 v = *(const float4*)&h[(size_t)j * CH + c4];
    float vv[4] = {v.x, v.y, v.z, v.w};
    float o[4];
#pragma unroll
    for (int i = 0; i < 4; ++i) {
        int c = c4 + i;
        float m = s1[c] * inv_n;
        float msq = s2[c] * inv_n;
        float a = ga[c];
        float var = msq + m * m * (a * a - 2.f * a);
        float r = rsqrtf(var + cEPS);
        float cv = vv[i] - a * m;
        float ov = gw[c] * cv * r + gb[c];
        if (do_relu) ov = fmaxf(ov, 0.f);
        o[i] = ov;
    }
    *(float4*)&h[(size_t)j * CH + c4] = make_float4(o[0], o[1], o[2], o[3]);
}

extern "C" void kernel_launch(void* const* d_in, const int* in_sizes, int n_in,
                              void* d_out, int out_size, void* d_ws, size_t ws_size,
                              hipStream_t stream) {
    const float* x    = (const float*)d_in[0];
    const float* res1 = (const float*)d_in[1];
    const float* res2 = (const float*)d_in[2];
    const float* ew1  = (const float*)d_in[3];
    const float* ew2  = (const float*)d_in[4];
    const float* W1   = (const float*)d_in[5];
    const float* b1   = (const float*)d_in[6];
    const float* W2   = (const float*)d_in[7];
    const float* b2   = (const float*)d_in[8];
    const float* g1w  = (const float*)d_in[9];
    const float* g1b  = (const float*)d_in[10];
    const float* g1a  = (const float*)d_in[11];
    const float* g2w  = (const float*)d_in[12];
    const float* g2b  = (const float*)d_in[13];
    const float* g2a  = (const float*)d_in[14];
    const int* ei1    = (const int*)d_in[15];
    const int* ei2    = (const int*)d_in[16];
    const int* perm1  = (const int*)d_in[17];
    const int* perm2  = (const int*)d_in[18];
    float* out = (float*)d_out;

    // workspace layout (floats). ~112 MB total.
    size_t NC0 = (size_t)cN0 * CH;  // 12.8M
    size_t NC1 = (size_t)cN1 * CH;  // 6.4M
    float* ws_f  = (float*)d_ws;
    float* upbuf = ws_f;                  // up1 (N1*C) then up2 (N0*C)
    float* hW1   = ws_f + NC0;            // N1*C
    float* h1    = ws_f + NC0 + NC1;      // N1*C (layer-1 accumulator / normalized h)
    float* hW2   = ws_f + NC0;            // N0*C (overlaps hW1+h1, both dead by then)
    float* deg   = ws_f + 2 * NC0;        // N0
    float* stats = deg + cN0;             // 1024 floats
    int*   inv   = (int*)(stats + 1024);  // N0 ints
    int*   hist  = inv + cN0;             // N0 ints (CSR cursor)
    int*   off   = hist + cN0;            // N0+1 ints
    int*   csr_row = off + cN0 + 1;       // E2 ints
    float* csr_val = (float*)(csr_row + cE2);  // E2 floats
    int*   bsum  = (int*)(csr_val + cE2); // <=128 ints (scan block sums)

    float* s1x = stats + 0;   float* s2x = stats + 128;  // x stats
    float* s1a = stats + 256; float* s2a = stats + 384;  // layer-1 GCN-out stats
    float* sh1 = stats + 512; float* sh2 = stats + 640;  // h1 colsum
    float* s1b = stats + 768; float* s2b = stats + 896;  // layer-2 GCN-out stats

    hipMemsetAsync(stats, 0, 1024 * sizeof(float), stream);

    int nb1 = cdiv(cN1, SCAN_ITEMS), nb0 = cdiv(cN0, SCAN_ITEMS);

    // ---- layer 0: N2 -> N1 ----
    colstats_kernel<<<512, 256, 0, stream>>>(x, cN2, s1x, s2x);
    fill_inv_kernel<<<cdiv(cN1, 256), 256, 0, stream>>>(inv, cN1);
    scatter_inv_kernel<<<cdiv(cN2, 256), 256, 0, stream>>>(perm1, inv, cN2);
    unpool_kernel<<<cdiv(cN1 * 32, 256), 256, 0, stream>>>(x, inv, s1x, 1.f / cN2, res1, upbuf, cN1);

    hipMemsetAsync(deg, 0, (size_t)cN1 * sizeof(float), stream);
    hipMemsetAsync(hist, 0, (size_t)cN1 * sizeof(int), stream);
    edge_deg_hist_kernel<<<cdiv(cE1, 256), 256, 0, stream>>>(ei1 + cE1, ew1, deg, hist, cE1);
    dinv_kernel<<<cdiv(cN1, 256), 256, 0, stream>>>(deg, cN1);

    scan_reduce_kernel<<<nb1, 256, 0, stream>>>(hist, bsum, cN1);
    scan_blocksums_kernel<<<1, 1024, 0, stream>>>(bsum, nb1);
    scan_apply_kernel<<<nb1, 256, 0, stream>>>(hist, bsum, off, hist, cN1);  // hist becomes cursor
    csr_scatter_kernel<<<cdiv(cE1, 256), 256, 0, stream>>>(ei1, ei1 + cE1, ew1, deg, hist, csr_row, csr_val, cE1);

    gemm128_fused_kernel<<<cdiv(cN1, 32), 256, 0, stream>>>(upbuf, W1, deg, b1, hW1, h1, cN1);
    gather_kernel<<<cdiv(cN1, 4), 256, 0, stream>>>(hW1, off, csr_row, csr_val, h1, cN1);

    colstats_kernel<<<512, 256, 0, stream>>>(h1, cN1, s1a, s2a);
    norm_kernel<<<cdiv(cN1 * 32, 256), 256, 0, stream>>>(h1, s1a, s2a, g1w, g1b, g1a, 1.f / cN1, cN1, 1);
    colstats_kernel<<<512, 256, 0, stream>>>(h1, cN1, sh1, sh2);

    // ---- layer 1: N1 -> N0 ----
    fill_inv_kernel<<<cdiv(cN0, 256), 256, 0, stream>>>(inv, cN0);
    scatter_inv_kernel<<<cdiv(cN1, 256), 256, 0, stream>>>(perm2, inv, cN1);
    unpool_kernel<<<cdiv(cN0 * 32, 256), 256, 0, stream>>>(h1, inv, sh1, 1.f / cN1, res2, upbuf, cN0);

    hipMemsetAsync(deg, 0, (size_t)cN0 * sizeof(float), stream);
    hipMemsetAsync(hist, 0, (size_t)cN0 * sizeof(int), stream);
    edge_deg_hist_kernel<<<cdiv(cE2, 256), 256, 0, stream>>>(ei2 + cE2, ew2, deg, hist, cE2);
    dinv_kernel<<<cdiv(cN0, 256), 256, 0, stream>>>(deg, cN0);

    scan_reduce_kernel<<<nb0, 256, 0, stream>>>(hist, bsum, cN0);
    scan_blocksums_kernel<<<1, 1024, 0, stream>>>(bsum, nb0);
    scan_apply_kernel<<<nb0, 256, 0, stream>>>(hist, bsum, off, hist, cN0);  // hist becomes cursor
    csr_scatter_kernel<<<cdiv(cE2, 256), 256, 0, stream>>>(ei2, ei2 + cE2, ew2, deg, hist, csr_row, csr_val, cE2);

    gemm128_fused_kernel<<<cdiv(cN0, 32), 256, 0, stream>>>(upbuf, W2, deg, b2, hW2, out, cN0);
    gather_kernel<<<cdiv(cN0, 4), 256, 0, stream>>>(hW2, off, csr_row, csr_val, out, cN0);

    colstats_kernel<<<512, 256, 0, stream>>>(out, cN0, s1b, s2b);
    norm_kernel<<<cdiv(cN0 * 32, 256), 256, 0, stream>>>(out, s1b, s2b, g2w, g2b, g2a, 1.f / cN0, cN0, 0);
}

// Round 12
// 735.994 us; speedup vs baseline: 4.3265x; 1.0749x over previous
//
#include <hip/hip_runtime.h>

#define CH 128
constexpr int cN2 = 25000, cN1 = 50000, cN0 = 100000;
constexpr int cE1 = 500000, cE2 = 1000000;
constexpr float cEPS = 1e-5f;

static inline int cdiv(int a, int b) { return (a + b - 1) / b; }

// per-channel sum and sum-of-squares over rows
__global__ __launch_bounds__(256) void colstats_kernel(const float* __restrict__ in, int n,
                                                       float* __restrict__ s1, float* __restrict__ s2) {
    int tid = threadIdx.x;
    int c = tid & 127;
    int h = tid >> 7;  // 0/1
    float a1 = 0.f, a2 = 0.f;
    for (int r = blockIdx.x * 2 + h; r < n; r += gridDim.x * 2) {
        float v = in[(size_t)r * CH + c];
        a1 += v;
        a2 += v * v;
    }
    __shared__ float l1[256], l2[256];
    l1[tid] = a1;
    l2[tid] = a2;
    __syncthreads();
    if (h == 0) {
        a1 += l1[tid + 128];
        a2 += l2[tid + 128];
        unsafeAtomicAdd(&s1[c], a1);
        unsafeAtomicAdd(&s2[c], a2);
    }
}

__global__ __launch_bounds__(256) void fill_inv_kernel(int* __restrict__ inv, int n) {
    int i = blockIdx.x * 256 + threadIdx.x;
    if (i < n) inv[i] = -1;
}

__global__ __launch_bounds__(256) void scatter_inv_kernel(const int* __restrict__ perm, int* __restrict__ inv, int m) {
    int i = blockIdx.x * 256 + threadIdx.x;
    if (i < m) inv[perm[i]] = i;
}

// out[j] = (inv[j]>=0 ? src[inv[j]] : colsum*inv_cnt) + res[j]
__global__ __launch_bounds__(256) void unpool_kernel(const float* __restrict__ src, const int* __restrict__ inv,
                                                     const float* __restrict__ colsum, float inv_cnt,
                                                     const float* __restrict__ res, float* __restrict__ out, int n) {
    int idx = blockIdx.x * 256 + threadIdx.x;
    if (idx >= n * 32) return;
    int j = idx >> 5;
    int c4 = (idx & 31) * 4;
    int iv = inv[j];
    float4 v;
    if (iv >= 0) {
        v = *(const float4*)&src[(size_t)iv * CH + c4];
    } else {
        v.x = colsum[c4 + 0] * inv_cnt;
        v.y = colsum[c4 + 1] * inv_cnt;
        v.z = colsum[c4 + 2] * inv_cnt;
        v.w = colsum[c4 + 3] * inv_cnt;
    }
    float rv = res[j];
    v.x += rv; v.y += rv; v.z += rv; v.w += rv;
    *(float4*)&out[(size_t)j * CH + c4] = v;
}

// histogram of edge cols: 1 int atomic per edge (r10: fused deg+hist = 2 atomics/edge
// dirtied 64B/atomic -> 62MB writeback, 90us; halving atomics halves that)
__global__ __launch_bounds__(256) void edge_hist_kernel(const int* __restrict__ col, int* __restrict__ hist, int E) {
    int e = blockIdx.x * 256 + threadIdx.x;
    if (e < E) atomicAdd(&hist[col[e]], 1);
}

// --- hierarchical exclusive scan (3-dispatch, coalesced; r9 single-block was 227us) ---
constexpr int SCAN_ITEMS = 1024;  // items per block, 4 per thread

__global__ __launch_bounds__(256) void scan_reduce_kernel(const int* __restrict__ cnt, int* __restrict__ bsum, int n) {
    __shared__ int lds[256];
    int base = blockIdx.x * SCAN_ITEMS;
    int sum = 0;
    for (int i = threadIdx.x; i < SCAN_ITEMS; i += 256) {
        int idx = base + i;
        sum += (idx < n) ? cnt[idx] : 0;
    }
    lds[threadIdx.x] = sum;
    __syncthreads();
    for (int ofs = 128; ofs > 0; ofs >>= 1) {
        if (threadIdx.x < ofs) lds[threadIdx.x] += lds[threadIdx.x + ofs];
        __syncthreads();
    }
    if (threadIdx.x == 0) bsum[blockIdx.x] = lds[0];
}

__global__ __launch_bounds__(1024) void scan_blocksums_kernel(int* __restrict__ bsum, int nb) {
    __shared__ int lds[1024];
    int tid = threadIdx.x;
    int v = (tid < nb) ? bsum[tid] : 0;
    lds[tid] = v;
    __syncthreads();
    for (int ofs = 1; ofs < 1024; ofs <<= 1) {
        int t = (tid >= ofs) ? lds[tid - ofs] : 0;
        __syncthreads();
        lds[tid] += t;
        __syncthreads();
    }
    if (tid < nb) bsum[tid] = lds[tid] - v;  // exclusive
}

__global__ __launch_bounds__(256) void scan_apply_kernel(const int* __restrict__ cnt, const int* __restrict__ bsum,
                                                         int* __restrict__ off, int* __restrict__ cursor, int n) {
    __shared__ int lds[256];
    int tid = threadIdx.x;
    int idx0 = blockIdx.x * SCAN_ITEMS + tid * 4;
    int v[4];
#pragma unroll
    for (int j = 0; j < 4; ++j) {
        int idx = idx0 + j;
        v[j] = (idx < n) ? cnt[idx] : 0;
    }
    int tsum = v[0] + v[1] + v[2] + v[3];
    lds[tid] = tsum;
    __syncthreads();
    for (int ofs = 1; ofs < 256; ofs <<= 1) {
        int t = (tid >= ofs) ? lds[tid - ofs] : 0;
        __syncthreads();
        lds[tid] += t;
        __syncthreads();
    }
    int run = bsum[blockIdx.x] + lds[tid] - tsum;
#pragma unroll
    for (int j = 0; j < 4; ++j) {
        int idx = idx0 + j;
        if (idx < n) {
            off[idx] = run;
            cursor[idx] = run;
        }
        run += v[j];
    }
    if (blockIdx.x == gridDim.x - 1 && tid == 255) off[n] = run;
}

// scatter packed (row, ew) into CSR buckets via atomic cursor — one 8B store per edge
__global__ __launch_bounds__(256) void csr_scatter_kernel(const int* __restrict__ rows, const int* __restrict__ cols,
                                                          const float* __restrict__ ew,
                                                          int* __restrict__ cursor, int2* __restrict__ csr_pair, int E) {
    int e = blockIdx.x * 256 + threadIdx.x;
    if (e >= E) return;
    int r = rows[e];
    int c = cols[e];
    int p = atomicAdd(&cursor[c], 1);
    csr_pair[p] = make_int2(r, __float_as_int(ew[e]));
}

// deg from CSR segment sum (contiguous, NO atomics), then dinv = rsqrt(deg+1)
__global__ __launch_bounds__(256) void deg_dinv_kernel(const int* __restrict__ off, const int2* __restrict__ csr_pair,
                                                       float* __restrict__ dinv, int n) {
    int i = blockIdx.x * 256 + threadIdx.x;
    if (i >= n) return;
    int s = off[i], e = off[i + 1];
    float d = 1.0f;  // self-loop weight
    for (int p = s; p < e; ++p) d += __int_as_float(csr_pair[p].y);
    dinv[i] = rsqrtf(d);
}

// Out[n x 128] = A[n x 128] @ W[128 x 128], fp32, fused self-loop epilogue.
// W (64KB) + 32-row A tile (16KB) in LDS; 4 rows x 4 cols per thread; k-loop
// unrolled only 2x to keep VGPRs < 128.
__global__ __launch_bounds__(256) void gemm128_fused_kernel(const float* __restrict__ A, const float* __restrict__ W,
                                                            const float* __restrict__ dinv, const float* __restrict__ bias,
                                                            float* __restrict__ hW, float* __restrict__ outinit, int n) {
    __shared__ float Ws[CH * CH];   // 64 KB
    __shared__ float As[32 * CH];   // 16 KB
    int tid = threadIdx.x;
    for (int i = tid * 4; i < CH * CH; i += 256 * 4)
        *(float4*)&Ws[i] = *(const float4*)&W[i];
    int rowbase = blockIdx.x * 32;
    for (int i = tid; i < 32 * 32; i += 256) {
        int r = i >> 5, c4 = (i & 31) * 4;
        int gr = min(rowbase + r, n - 1);
        *(float4*)&As[r * CH + c4] = *(const float4*)&A[(size_t)gr * CH + c4];
    }
    __syncthreads();

    int rg = (tid >> 5) * 4;
    int cc = (tid & 31) * 4;
    float acc[4][4] = {};
#pragma unroll 2
    for (int k = 0; k < CH; k += 4) {
        float4 a[4];
#pragma unroll
        for (int r = 0; r < 4; ++r) a[r] = *(const float4*)&As[(rg + r) * CH + k];
#pragma unroll
        for (int s = 0; s < 4; ++s) {
            float4 wv = *(const float4*)&Ws[(k + s) * CH + cc];
#pragma unroll
            for (int r = 0; r < 4; ++r) {
                float as = (s == 0) ? a[r].x : (s == 1) ? a[r].y : (s == 2) ? a[r].z : a[r].w;
                acc[r][0] += as * wv.x;
                acc[r][1] += as * wv.y;
                acc[r][2] += as * wv.z;
                acc[r][3] += as * wv.w;
            }
        }
    }
#pragma unroll
    for (int r = 0; r < 4; ++r) {
        int gr = rowbase + rg + r;
        if (gr < n) {
            float4 v = make_float4(acc[r][0], acc[r][1], acc[r][2], acc[r][3]);
            *(float4*)&hW[(size_t)gr * CH + cc] = v;
            float d = dinv[gr];
            float s = d * d;
            float4 o;
            o.x = v.x * s + bias[cc + 0];
            o.y = v.y * s + bias[cc + 1];
            o.z = v.z * s + bias[cc + 2];
            o.w = v.w * s + bias[cc + 3];
            *(float4*)&outinit[(size_t)gr * CH + cc] = o;
        }
    }
}

// CSR gather: one wave per node, float2 per lane.
// out[c] = init[c] + dinv[c] * sum_p (ew_p * dinv[row_p]) * hW[row_p]
__global__ __launch_bounds__(256) void gather_kernel(const float* __restrict__ hW, const int* __restrict__ off,
                                                     const int2* __restrict__ csr_pair, const float* __restrict__ dinv,
                                                     float* __restrict__ out, int n) {
    int lane = threadIdx.x & 63;
    int node = blockIdx.x * 4 + (threadIdx.x >> 6);
    if (node >= n) return;
    int s = off[node], e = off[node + 1];
    float ax = 0.f, ay = 0.f;
    int i = s;
    for (; i + 1 < e; i += 2) {
        int2 p0 = csr_pair[i], p1 = csr_pair[i + 1];
        float v0 = __int_as_float(p0.y) * dinv[p0.x];
        float v1 = __int_as_float(p1.y) * dinv[p1.x];
        float2 h0 = *(const float2*)&hW[(size_t)p0.x * CH + lane * 2];
        float2 h1 = *(const float2*)&hW[(size_t)p1.x * CH + lane * 2];
        ax += v0 * h0.x + v1 * h1.x;
        ay += v0 * h0.y + v1 * h1.y;
    }
    if (i < e) {
        int2 p0 = csr_pair[i];
        float v0 = __int_as_float(p0.y) * dinv[p0.x];
        float2 h0 = *(const float2*)&hW[(size_t)p0.x * CH + lane * 2];
        ax += v0 * h0.x;
        ay += v0 * h0.y;
    }
    float dc = dinv[node];
    float2 o = *(float2*)&out[(size_t)node * CH + lane * 2];  // self-loop + bias init from gemm epilogue
    o.x += dc * ax;
    o.y += dc * ay;
    *(float2*)&out[(size_t)node * CH + lane * 2] = o;
}

// GraphNorm (optionally ReLU) in place, from per-channel S1/S2
__global__ __launch_bounds__(256) void norm_kernel(float* __restrict__ h, const float* __restrict__ s1,
                                                   const float* __restrict__ s2, const float* __restrict__ gw,
                                                   const float* __restrict__ gb, const float* __restrict__ ga,
                                                   float inv_n, int n, int do_relu) {
    int idx = blockIdx.x * 256 + threadIdx.x;
    if (idx >= n * 32) return;
    int j = idx >> 5;
    int c4 = (idx & 31) * 4;
    float4 v = *(const float4*)&h[(size_t)j * CH + c4];
    float vv[4] = {v.x, v.y, v.z, v.w};
    float o[4];
#pragma unroll
    for (int i = 0; i < 4; ++i) {
        int c = c4 + i;
        float m = s1[c] * inv_n;
        float msq = s2[c] * inv_n;
        float a = ga[c];
        float var = msq + m * m * (a * a - 2.f * a);
        float r = rsqrtf(var + cEPS);
        float cv = vv[i] - a * m;
        float ov = gw[c] * cv * r + gb[c];
        if (do_relu) ov = fmaxf(ov, 0.f);
        o[i] = ov;
    }
    *(float4*)&h[(size_t)j * CH + c4] = make_float4(o[0], o[1], o[2], o[3]);
}

extern "C" void kernel_launch(void* const* d_in, const int* in_sizes, int n_in,
                              void* d_out, int out_size, void* d_ws, size_t ws_size,
                              hipStream_t stream) {
    const float* x    = (const float*)d_in[0];
    const float* res1 = (const float*)d_in[1];
    const float* res2 = (const float*)d_in[2];
    const float* ew1  = (const float*)d_in[3];
    const float* ew2  = (const float*)d_in[4];
    const float* W1   = (const float*)d_in[5];
    const float* b1   = (const float*)d_in[6];
    const float* W2   = (const float*)d_in[7];
    const float* b2   = (const float*)d_in[8];
    const float* g1w  = (const float*)d_in[9];
    const float* g1b  = (const float*)d_in[10];
    const float* g1a  = (const float*)d_in[11];
    const float* g2w  = (const float*)d_in[12];
    const float* g2b  = (const float*)d_in[13];
    const float* g2a  = (const float*)d_in[14];
    const int* ei1    = (const int*)d_in[15];
    const int* ei2    = (const int*)d_in[16];
    const int* perm1  = (const int*)d_in[17];
    const int* perm2  = (const int*)d_in[18];
    float* out = (float*)d_out;

    // workspace layout (floats). ~112 MB total.
    size_t NC0 = (size_t)cN0 * CH;  // 12.8M
    size_t NC1 = (size_t)cN1 * CH;  // 6.4M
    float* ws_f  = (float*)d_ws;
    float* upbuf = ws_f;                  // up1 (N1*C) then up2 (N0*C)
    float* hW1   = ws_f + NC0;            // N1*C
    float* h1    = ws_f + NC0 + NC1;      // N1*C
    float* hW2   = ws_f + NC0;            // N0*C (overlaps hW1+h1, both dead by then)
    float* dinv  = ws_f + 2 * NC0;        // N0 (rsqrt degree)
    float* stats = dinv + cN0;            // 1024 floats
    int*   inv   = (int*)(stats + 1024);  // N0 ints
    int*   hist  = inv + cN0;             // N0 ints (CSR cursor after scan)
    int*   off   = hist + cN0;            // N0+1 ints
    int2*  csr_pair = (int2*)(off + cN0 + 1);  // E2 pairs (8B each)
    int*   bsum  = (int*)(csr_pair + cE2);     // <=128 ints

    float* s1x = stats + 0;   float* s2x = stats + 128;  // x stats
    float* s1a = stats + 256; float* s2a = stats + 384;  // layer-1 GCN-out stats
    float* sh1 = stats + 512; float* sh2 = stats + 640;  // h1 colsum
    float* s1b = stats + 768; float* s2b = stats + 896;  // layer-2 GCN-out stats

    hipMemsetAsync(stats, 0, 1024 * sizeof(float), stream);

    int nb1 = cdiv(cN1, SCAN_ITEMS), nb0 = cdiv(cN0, SCAN_ITEMS);

    // ---- layer 0: N2 -> N1 ----
    colstats_kernel<<<512, 256, 0, stream>>>(x, cN2, s1x, s2x);
    fill_inv_kernel<<<cdiv(cN1, 256), 256, 0, stream>>>(inv, cN1);
    scatter_inv_kernel<<<cdiv(cN2, 256), 256, 0, stream>>>(perm1, inv, cN2);
    unpool_kernel<<<cdiv(cN1 * 32, 256), 256, 0, stream>>>(x, inv, s1x, 1.f / cN2, res1, upbuf, cN1);

    hipMemsetAsync(hist, 0, (size_t)cN1 * sizeof(int), stream);
    edge_hist_kernel<<<cdiv(cE1, 256), 256, 0, stream>>>(ei1 + cE1, hist, cE1);
    scan_reduce_kernel<<<nb1, 256, 0, stream>>>(hist, bsum, cN1);
    scan_blocksums_kernel<<<1, 1024, 0, stream>>>(bsum, nb1);
    scan_apply_kernel<<<nb1, 256, 0, stream>>>(hist, bsum, off, hist, cN1);  // hist becomes cursor
    csr_scatter_kernel<<<cdiv(cE1, 256), 256, 0, stream>>>(ei1, ei1 + cE1, ew1, hist, csr_pair, cE1);
    deg_dinv_kernel<<<cdiv(cN1, 256), 256, 0, stream>>>(off, csr_pair, dinv, cN1);

    gemm128_fused_kernel<<<cdiv(cN1, 32), 256, 0, stream>>>(upbuf, W1, dinv, b1, hW1, h1, cN1);
    gather_kernel<<<cdiv(cN1, 4), 256, 0, stream>>>(hW1, off, csr_pair, dinv, h1, cN1);

    colstats_kernel<<<512, 256, 0, stream>>>(h1, cN1, s1a, s2a);
    norm_kernel<<<cdiv(cN1 * 32, 256), 256, 0, stream>>>(h1, s1a, s2a, g1w, g1b, g1a, 1.f / cN1, cN1, 1);
    colstats_kernel<<<512, 256, 0, stream>>>(h1, cN1, sh1, sh2);

    // ---- layer 1: N1 -> N0 ----
    fill_inv_kernel<<<cdiv(cN0, 256), 256, 0, stream>>>(inv, cN0);
    scatter_inv_kernel<<<cdiv(cN1, 256), 256, 0, stream>>>(perm2, inv, cN1);
    unpool_kernel<<<cdiv(cN0 * 32, 256), 256, 0, stream>>>(h1, inv, sh1, 1.f / cN1, res2, upbuf, cN0);

    hipMemsetAsync(hist, 0, (size_t)cN0 * sizeof(int), stream);
    edge_hist_kernel<<<cdiv(cE2, 256), 256, 0, stream>>>(ei2 + cE2, hist, cE2);
    scan_reduce_kernel<<<nb0, 256, 0, stream>>>(hist, bsum, cN0);
    scan_blocksums_kernel<<<1, 1024, 0, stream>>>(bsum, nb0);
    scan_apply_kernel<<<nb0, 256, 0, stream>>>(hist, bsum, off, hist, cN0);  // hist becomes cursor
    csr_scatter_kernel<<<cdiv(cE2, 256), 256, 0, stream>>>(ei2, ei2 + cE2, ew2, hist, csr_pair, cE2);
    deg_dinv_kernel<<<cdiv(cN0, 256), 256, 0, stream>>>(off, csr_pair, dinv, cN0);

    gemm128_fused_kernel<<<cdiv(cN0, 32), 256, 0, stream>>>(upbuf, W2, dinv, b2, hW2, out, cN0);
    gather_kernel<<<cdiv(cN0, 4), 256, 0, stream>>>(hW2, off, csr_pair, dinv, out, cN0);

    colstats_kernel<<<512, 256, 0, stream>>>(out, cN0, s1b, s2b);
    norm_kernel<<<cdiv(cN0 * 32, 256), 256, 0, stream>>>(out, s1b, s2b, g2w, g2b, g2a, 1.f / cN0, cN0, 0);
}